// Round 13
// baseline (44.438 us; speedup 1.0000x reference)
//
#include <hip/hip_runtime.h>

#define NROWS 8192
#define DIM   256          // elements per row == bytes per row in fp8
#define BHALF 4096
#define NCHUNK 8           // col chunks per 128-row panel (1024 cols each)
#define SCALE 1.69864358f  // sqrt(2 * log2(e)): dot = sim * log2(e)
#define LN2F  0.69314718f

typedef unsigned char u8;
typedef __attribute__((ext_vector_type(16))) float f32x16;
typedef __attribute__((ext_vector_type(4))) int   i32x4;
typedef __attribute__((ext_vector_type(8))) int   i32x8;

__device__ inline void gload_lds16(const void* g, void* l) {
  __builtin_amdgcn_global_load_lds(
      (const __attribute__((address_space(1))) void*)g,
      (__attribute__((address_space(3))) void*)l, 16, 0, 0);
}

// exact OCP e4m3fn -> f32 (values here never reach NaN/448)
__device__ inline float fp8_to_f32(int b) {
  const int e = (b >> 3) & 15, m = b & 7;
  float mag = e ? __builtin_bit_cast(float, ((e + 120) << 23) | (m << 20))
                : (float)m * 0x1p-9f;
  return (b & 128) ? -mag : mag;
}

// Kernel 1: row-PAIR normalize (rows r and r+B together): quantize to fp8
// (scaled by sqrt(2*log2e) so Gram dot = sim*log2e), and precompute from the
// DEQUANTIZED values pos[r] (positive-pair dot, nats) and diag[r] (self-dot,
// log2 units). Zeroes rowsum / cnt / out (stream-ordered before sim).
__global__ __launch_bounds__(256) void nrm_kernel(const float* __restrict__ zi,
                                                  const float* __restrict__ zj,
                                                  u8* __restrict__ zn8,
                                                  float* __restrict__ rowsum,
                                                  float* __restrict__ pos,
                                                  float* __restrict__ diag,
                                                  int* __restrict__ cnt,
                                                  float* __restrict__ out) {
  const int t = threadIdx.x, b = blockIdx.x;
  const int gid = b * 256 + t;
  if (gid < NROWS) rowsum[gid] = 0.f;
  if (gid < 64) cnt[gid] = 0;
  if (gid == 0) out[0] = 0.f;

  const int w = t >> 6, l = t & 63;
#pragma unroll
  for (int q = 0; q < 2; ++q) {
    const int p = b * 8 + w * 2 + q;           // pair index 0..4095
    float4 vi = *(const float4*)(zi + (size_t)p * DIM + l * 4);
    float4 vj = *(const float4*)(zj + (size_t)p * DIM + l * 4);
    float ssi = vi.x * vi.x + vi.y * vi.y + vi.z * vi.z + vi.w * vi.w;
    float ssj = vj.x * vj.x + vj.y * vj.y + vj.z * vj.z + vj.w * vj.w;
#pragma unroll
    for (int m = 1; m < 64; m <<= 1) {
      ssi += __shfl_xor(ssi, m);
      ssj += __shfl_xor(ssj, m);
    }
    const float invi = SCALE / fmaxf(sqrtf(ssi), 1e-8f);
    const float invj = SCALE / fmaxf(sqrtf(ssj), 1e-8f);
    int pi = __builtin_amdgcn_cvt_pk_fp8_f32(vi.x * invi, vi.y * invi, 0, false);
    pi = __builtin_amdgcn_cvt_pk_fp8_f32(vi.z * invi, vi.w * invi, pi, true);
    int pj = __builtin_amdgcn_cvt_pk_fp8_f32(vj.x * invj, vj.y * invj, 0, false);
    pj = __builtin_amdgcn_cvt_pk_fp8_f32(vj.z * invj, vj.w * invj, pj, true);
    *(int*)(zn8 + (size_t)p * DIM + l * 4) = pi;
    *(int*)(zn8 + (size_t)(p + BHALF) * DIM + l * 4) = pj;

    // dequantized dot / self-dots (match MFMA values to summation rounding)
    float dot = 0.f, di = 0.f, dj = 0.f;
#pragma unroll
    for (int k2 = 0; k2 < 4; ++k2) {
      const float qi = fp8_to_f32((pi >> (8 * k2)) & 255);
      const float qj = fp8_to_f32((pj >> (8 * k2)) & 255);
      dot += qi * qj; di += qi * qi; dj += qj * qj;
    }
#pragma unroll
    for (int m = 1; m < 64; m <<= 1) {
      dot += __shfl_xor(dot, m);
      di  += __shfl_xor(di, m);
      dj  += __shfl_xor(dj, m);
    }
    if      (l == 0) pos[p] = dot * LN2F;            // nats
    else if (l == 1) pos[p + BHALF] = dot * LN2F;
    else if (l == 2) diag[p] = di;                   // log2 units
    else if (l == 3) diag[p + BHALF] = dj;
  }
}

// Kernel 2: full-matrix row-sum sweep, 512-thread blocks -> 4 waves/SIMD
// (vs 2 in all prior configs). Same per-block geometry (128 panel rows x
// 1024 cols, 8 streamed 128-col tiles, 1 barrier/tile, depth-1 prefetch);
// wave (ws,wp) owns tile-strip ws*32 (A) x panel-half wp*64 (B). 9 nulls
// showed the loop is latency-bound with 2 streams/SIMD; this doubles the
// independent instruction streams without touching amortization.
__global__ __launch_bounds__(512, 4) void sim_kernel(const u8* __restrict__ zn8,
                                                     float* __restrict__ rowsum,
                                                     const float* __restrict__ pos,
                                                     const float* __restrict__ diag,
                                                     int* __restrict__ cnt,
                                                     float* __restrict__ out) {
  __shared__ __align__(16) u8 Bsm[2][128 * DIM];   // 2 x 32 KB
  __shared__ float plane[4][128];
  __shared__ float wsum[2];
  __shared__ int sfin;

  const int t = threadIdx.x;
  const int w = t >> 6, l = t & 63;     // 8 waves
  const int ws = w >> 1, wp = w & 1;    // tile strip / panel half
  const int n31 = l & 31, kh = l >> 5;  // operand row / k-half

  const int rp = (int)blockIdx.x >> 3;  // row panel 0..63
  const int ch = (int)blockIdx.x & 7;   // col chunk 0..7
  const int colbase = ch * 1024;        // zn8 row index of first streamed tile

  // staging bases (i-invariant: r&7 == (t>>4)&7, so swizzle salt is fixed)
  const int cd = t & 15;
  const int cs = (cd & 8) | ((cd ^ (t >> 4)) & 7);
  const int sbase = (t >> 4) * DIM + cs * 16;      // source byte offset, i=0
  const int dbase = t * 16;                        // dest byte offset, i=0
  auto STAGE = [&](int base_row, u8* dst) {        // 4 loads (i stride 8 KB)
#pragma unroll
    for (int i = 0; i < 4; ++i)
      gload_lds16(zn8 + (size_t)base_row * DIM + sbase + i * 8192,
                  dst + dbase + i * 8192);
  };
  // swizzled fragment read for 32x32x64: 32B of row `row`, k-step kk (0..3).
  // logical chunks c0,c0+1 with c0 = kk*4 + kh*2; phys = (c&8)|((c^salt)&7).
  // (verified end-to-end in r8/r12: absmax 0)
  auto RD32 = [&](const u8* buf, int row, int kk) -> i32x8 {
    const int salt = row & 7;
    const u8* base = buf + row * DIM;
    const int c0 = kk * 4 + kh * 2;
    i32x4 lo = *(const i32x4*)(base + (((c0 & 8) | ((c0 ^ salt) & 7)) << 4));
    i32x4 hi = *(const i32x4*)(base + ((((c0 + 1) & 8) | (((c0 + 1) ^ salt) & 7)) << 4));
    return __builtin_shufflevector(lo, hi, 0, 1, 2, 3, 4, 5, 6, 7);
  };

  STAGE(rp * 128, &Bsm[0][0]);          // panel -> buf0 (4 loads)
  STAGE(colbase, &Bsm[1][0]);           // tile0 -> buf1 (4 more, 8 in flight)
  asm volatile("s_waitcnt vmcnt(4)" ::: "memory");   // panel landed
  __builtin_amdgcn_sched_barrier(0);
  __builtin_amdgcn_s_barrier();
  __builtin_amdgcn_sched_barrier(0);

  i32x8 pb[2][4];                       // panel B-frags [pj][kk], 64 VGPR
#pragma unroll
  for (int pj = 0; pj < 2; ++pj)
#pragma unroll
    for (int kk = 0; kk < 4; ++kk)
      pb[pj][kk] = RD32(&Bsm[0][0], wp * 64 + pj * 32 + n31, kk);
  asm volatile("s_waitcnt lgkmcnt(0)" ::: "memory");
  __builtin_amdgcn_sched_barrier(0);
  // no barrier: tile0's barrier below also proves all waves finished pb reads

  float rsum[2] = {0.f, 0.f};
  f32x16 z16 = (f32x16)(0.f);           // persistent zero C (no per-tile init)

#pragma unroll 2
  for (int ti = 0; ti < 8; ++ti) {
    asm volatile("s_waitcnt vmcnt(0)" ::: "memory");  // tile ti landed (mine)
    __builtin_amdgcn_sched_barrier(0);
    __builtin_amdgcn_s_barrier();       // all waves: ti ready AND ti-1 readers done
    __builtin_amdgcn_sched_barrier(0);

    const u8* Bb = &Bsm[(ti + 1) & 1][0];            // tile ti's buffer
    if (ti < 7) STAGE(colbase + (ti + 1) * 128, &Bsm[ti & 1][0]);  // depth-1

    f32x16 acc[2];
#pragma unroll
    for (int kk = 0; kk < 4; ++kk) {
      i32x8 a = RD32(Bb, ws * 32 + n31, kk);         // JIT: 2 ds_read_b128
      asm volatile("s_waitcnt lgkmcnt(0)" ::: "memory");
      __builtin_amdgcn_sched_barrier(0);
      __builtin_amdgcn_s_setprio(1);
#pragma unroll
      for (int pj = 0; pj < 2; ++pj)
        acc[pj] = __builtin_amdgcn_mfma_scale_f32_32x32x64_f8f6f4(
            a, pb[pj][kk], (kk == 0) ? z16 : acc[pj],
            0, 0,                        // cbsz=fp8, blgp=fp8
            0, 0x7f7f7f7f,               // scale_a = 1.0 (e8m0 127)
            0, 0x7f7f7f7f);              // scale_b = 1.0
      __builtin_amdgcn_s_setprio(0);
    }

    // uniform epilogue: exp2 + lane-local row-sum (no special cases)
#pragma unroll
    for (int pj = 0; pj < 2; ++pj) {
      float e0 = 0.f, e1 = 0.f, e2 = 0.f, e3 = 0.f;
#pragma unroll
      for (int r16 = 0; r16 < 16; r16 += 4) {
        e0 += __builtin_amdgcn_exp2f(acc[pj][r16]);
        e1 += __builtin_amdgcn_exp2f(acc[pj][r16 + 1]);
        e2 += __builtin_amdgcn_exp2f(acc[pj][r16 + 2]);
        e3 += __builtin_amdgcn_exp2f(acc[pj][r16 + 3]);
      }
      rsum[pj] += (e0 + e1) + (e2 + e3);
    }
  }

  // panel row wp*64+pj*32+n lives in lanes n,n+32: one xor, then 4-plane sum
#pragma unroll
  for (int pj = 0; pj < 2; ++pj) {
    rsum[pj] += __shfl_xor(rsum[pj], 32);
    if (l < 32) plane[ws][wp * 64 + pj * 32 + l] = rsum[pj];
  }
  __syncthreads();

  // ---- fence-free fused finish ----
  if (t < 128)
    atomicAdd(&rowsum[rp * 128 + t],
              (plane[0][t] + plane[1][t]) + (plane[2][t] + plane[3][t]));
  asm volatile("s_waitcnt vmcnt(0)" ::: "memory");   // my atomics at coherence
  __syncthreads();
  if (t == 0) sfin = (atomicAdd(&cnt[rp], 1) == NCHUNK - 1);
  __syncthreads();
  if (sfin) {                           // 8th arrival: all panels' adds landed
    float v = 0.f;
    if (t < 128) {
      const int r = rp * 128 + t;
      float s = atomicAdd(&rowsum[r], 0.f);          // coherent read
      v = logf(s - __builtin_amdgcn_exp2f(diag[r])) - pos[r];
    }
#pragma unroll
    for (int m = 1; m < 64; m <<= 1) v += __shfl_xor(v, m);
    if (l == 0 && t < 128) wsum[w] = v;
    __syncthreads();
    if (t == 0) atomicAdd(out, (wsum[0] + wsum[1]) * (1.f / NROWS));
  }
}

extern "C" void kernel_launch(void* const* d_in, const int* in_sizes, int n_in,
                              void* d_out, int out_size, void* d_ws, size_t ws_size,
                              hipStream_t stream) {
  const float* zi = (const float*)d_in[0];
  const float* zj = (const float*)d_in[1];

  u8*    zn8    = (u8*)d_ws;                                        // 2 MB
  float* rowsum = (float*)((char*)d_ws + (size_t)NROWS * DIM);      // 32 KB
  float* pos    = (float*)((char*)rowsum + (size_t)NROWS * 4);      // 32 KB
  float* diag   = (float*)((char*)pos + (size_t)NROWS * 4);         // 32 KB
  int*   cnt    = (int*)((char*)diag + (size_t)NROWS * 4);          // 256 B
  float* out    = (float*)d_out;

  nrm_kernel<<<512, 256, 0, stream>>>(zi, zj, zn8, rowsum, pos, diag, cnt, out);
  sim_kernel<<<64 * NCHUNK, 512, 0, stream>>>(zn8, rowsum, pos, diag, cnt, out);
}